// Round 1
// baseline (1299.210 us; speedup 1.0000x reference)
//
#include <hip/hip_runtime.h>
#include <hip/hip_bf16.h>
#include <math.h>

#define NTOK 8192
#define DMODEL 1024
#define NEXP 32

typedef __attribute__((ext_vector_type(8))) short bf16x8;
typedef __attribute__((ext_vector_type(4))) float f32x4;

__device__ __forceinline__ unsigned int pk_bf16(float a, float b) {
  __hip_bfloat162 h = __float22bfloat162_rn(make_float2(a, b));
  union { __hip_bfloat162 h2; unsigned int u; } cv;
  cv.h2 = h;
  return cv.u;
}

__device__ __forceinline__ void gl_lds16(const unsigned short* g, unsigned short* l) {
  __builtin_amdgcn_global_load_lds(
      (const __attribute__((address_space(1))) unsigned int*)g,
      (__attribute__((address_space(3))) unsigned int*)l, 16, 0, 0);
}

// ---------------- x fp32 -> bf16 ----------------
__global__ __launch_bounds__(256) void convert_x(const float* __restrict__ x,
                                                 unsigned short* __restrict__ xb) {
  size_t i = (size_t)(blockIdx.x * 256 + threadIdx.x) * 8;
  float4 f0 = *reinterpret_cast<const float4*>(x + i);
  float4 f1 = *reinterpret_cast<const float4*>(x + i + 4);
  uint4 d;
  d.x = pk_bf16(f0.x, f0.y);
  d.y = pk_bf16(f0.z, f0.w);
  d.z = pk_bf16(f1.x, f1.y);
  d.w = pk_bf16(f1.z, f1.w);
  *reinterpret_cast<uint4*>(xb + i) = d;
}

// ---------------- W [E][K][N] fp32 -> Wt [E][N][K] bf16 ----------------
__global__ __launch_bounds__(256) void transpose_cvt2(const float* __restrict__ w,
                                                      unsigned short* __restrict__ wt) {
  int bid = blockIdx.x;
  int e = bid >> 8;
  int tk = (bid >> 4) & 15;
  int tn = bid & 15;
  const float* src = w + ((size_t)e << 20) + ((size_t)(tk * 64) << 10) + tn * 64;
  unsigned short* dst = wt + ((size_t)e << 20) + ((size_t)(tn * 64) << 10) + tk * 64;
  __shared__ unsigned int Ts[64 * 32];
  int t = threadIdx.x;
  {
    int kp = t >> 3;  // 0..31 (pair of k rows)
    int c8 = t & 7;   // col group of 8
    const float* s0 = src + (size_t)(2 * kp) * 1024 + c8 * 8;
    float4 a0 = *reinterpret_cast<const float4*>(s0);
    float4 a1 = *reinterpret_cast<const float4*>(s0 + 4);
    float4 b0 = *reinterpret_cast<const float4*>(s0 + 1024);
    float4 b1 = *reinterpret_cast<const float4*>(s0 + 1028);
    float av[8] = {a0.x, a0.y, a0.z, a0.w, a1.x, a1.y, a1.z, a1.w};
    float bv[8] = {b0.x, b0.y, b0.z, b0.w, b1.x, b1.y, b1.z, b1.w};
#pragma unroll
    for (int i = 0; i < 8; i++) {
      int n = c8 * 8 + i;
      Ts[n * 32 + (kp ^ (n & 28))] = pk_bf16(av[i], bv[i]);
    }
  }
  __syncthreads();
  {
    int n = t >> 2;
    int kq = t & 3;
#pragma unroll
    for (int h = 0; h < 2; h++) {
      int k4 = kq + h * 4;
      int phys4 = (4 * k4) ^ (n & 28);
      uint4 d = *reinterpret_cast<const uint4*>(&Ts[n * 32 + phys4]);
      *reinterpret_cast<uint4*>(dst + (size_t)n * 1024 + k4 * 8) = d;
    }
  }
}

// ---------------- gating ----------------
__global__ __launch_bounds__(256) void gate_partial(
    const float* __restrict__ x, const float* __restrict__ wg,
    float* __restrict__ partial) {
  __shared__ float Xs[256 * 20];
  int tid = threadIdx.x;
  int part = blockIdx.x >> 5;
  int tb = blockIdx.x & 31;
  int d0 = part * 128;
  float acc[32];
#pragma unroll
  for (int e = 0; e < 32; e++) acc[e] = 0.f;
  for (int ck = 0; ck < 8; ck++) {
    __syncthreads();
#pragma unroll
    for (int q = 0; q < 4; q++) {
      int li = q * 256 + tid;
      int row = li >> 2, j = li & 3;
      float4 v = *reinterpret_cast<const float4*>(
          x + (size_t)(tb * 256 + row) * DMODEL + d0 + ck * 16 + j * 4);
      *reinterpret_cast<float4*>(&Xs[row * 20 + j * 4]) = v;
    }
    __syncthreads();
#pragma unroll
    for (int d4 = 0; d4 < 4; d4++) {
      float4 xv = *reinterpret_cast<const float4*>(&Xs[tid * 20 + d4 * 4]);
      float xs[4] = {xv.x, xv.y, xv.z, xv.w};
#pragma unroll
      for (int dd = 0; dd < 4; dd++) {
        int d = d0 + ck * 16 + d4 * 4 + dd;
#pragma unroll
        for (int e = 0; e < 32; e++) acc[e] += xs[dd] * wg[d * 32 + e];
      }
    }
  }
  float* dst = partial + ((size_t)part * NTOK + tb * 256 + tid) * 32;
#pragma unroll
  for (int e = 0; e < 32; e += 4)
    *reinterpret_cast<float4*>(dst + e) =
        make_float4(acc[e], acc[e + 1], acc[e + 2], acc[e + 3]);
}

__global__ __launch_bounds__(256) void gate_top2(
    const float* __restrict__ partial, const float* __restrict__ bg,
    float* __restrict__ idx_out, int* __restrict__ eid,
    int* __restrict__ counts) {
  int t = blockIdx.x * 256 + threadIdx.x;
  float l[32];
#pragma unroll
  for (int e = 0; e < 32; e++) l[e] = bg[e];
  for (int p = 0; p < 8; p++) {
    const float* src = partial + ((size_t)p * NTOK + t) * 32;
#pragma unroll
    for (int e = 0; e < 32; e += 4) {
      float4 v = *reinterpret_cast<const float4*>(src + e);
      l[e] += v.x; l[e + 1] += v.y; l[e + 2] += v.z; l[e + 3] += v.w;
    }
  }
  int i0 = 0; float v0 = l[0];
#pragma unroll
  for (int e = 1; e < 32; e++)
    if (l[e] > v0) { v0 = l[e]; i0 = e; }
  int i1 = -1; float v1 = -3.0e38f;
#pragma unroll
  for (int e = 0; e < 32; e++)
    if (e != i0 && l[e] > v1) { v1 = l[e]; i1 = e; }
  *reinterpret_cast<float2*>(idx_out + t * 2) = make_float2((float)i0, (float)i1);
  eid[t * 2] = i0;
  eid[t * 2 + 1] = i1;
  atomicAdd(&counts[i0], 1);
  atomicAdd(&counts[i1], 1);
}

__global__ void scan_k(const int* __restrict__ counts, int* __restrict__ offsets) {
  if (threadIdx.x == 0) {
    int s = 0;
    for (int e = 0; e < 32; e++) { offsets[e] = s; s += counts[e]; }
    offsets[32] = s;
  }
}

__global__ __launch_bounds__(256) void build_stable(
    const int* __restrict__ eid, const int* __restrict__ offsets,
    int* __restrict__ tok_list) {
  int e = blockIdx.x;
  int tid = threadIdx.x;
  int lane = tid & 63, wv = tid >> 6;
  __shared__ int wcnt[4];
  int base = offsets[e];
  for (int c = 0; c < 64; c++) {
    int s = c * 256 + tid;
    bool f = (eid[s] == e);
    unsigned long long m = __ballot(f);
    if (lane == 0) wcnt[wv] = __popcll(m);
    __syncthreads();
    int woff = 0;
#pragma unroll
    for (int i = 0; i < 4; i++) woff += (i < wv) ? wcnt[i] : 0;
    int tot = wcnt[0] + wcnt[1] + wcnt[2] + wcnt[3];
    if (f) {
      int rank = woff + __popcll(m & ((1ull << lane) - 1ull));
      tok_list[base + rank] = s >> 1;
    }
    base += tot;
    __syncthreads();
  }
}

// ---------------- ragged GEMM v2: 256m x 256n tile, BK=32, 512 thr (8 waves
// as 2Mx4N, 128x64 per wave), double-buffered, 64KB LDS -> 2 blocks/CU.
// Per K-tile: 2 phases of {8 ds_read_b128 -> lgkmcnt(0)+sched_barrier ->
// setprio(1) -> 16 MFMA -> setprio(0)}; counted vmcnt(4) once per K-tile.
// LDS swizzle: physical 16B chunk p of row r holds logical k-chunk
// p ^ ((r>>1)&3)  (covers all 8 bank-groups across 16 consecutive rows ->
// conflict-free ds_read_b128; old (r&3) left a 4-way conflict). ----------------
template <int PHASE>
__global__ __launch_bounds__(512, 4) void moe_gemm3(
    const unsigned short* __restrict__ Wt, const float* __restrict__ bias,
    const unsigned short* __restrict__ Ain, unsigned short* __restrict__ Hout,
    float* __restrict__ out, const int* __restrict__ tok_list,
    const int* __restrict__ offsets, const int* __restrict__ counts) {
  // bx = nt*128 + mt*32 + e  (e in low bits -> experts spread over XCDs;
  // sibling tiles of one expert keep same bx%8 -> same XCD slot)
  int bx = blockIdx.x;
  int e = bx & 31;
  int mt = (bx >> 5) & 3;
  int nt = (bx >> 7) & 3;
  int n_e = counts[e];
  int m0 = mt * 256;
  if (m0 >= n_e) return;
  int n0 = nt * 256;
  int seg = offsets[e];

  __shared__ __align__(16) unsigned short As[2][256 * 32];
  __shared__ __align__(16) unsigned short Bs[2][256 * 32];

  int tid = threadIdx.x, lane = tid & 63, wid = tid >> 6;
  int wm = (wid >> 2) * 128, wn = (wid & 3) * 64;
  int ml = lane & 15, q = lane >> 4;

  // staging: wave wid stages A rows [wid*32, wid*32+32) and B rows same,
  // 2 A-loads + 2 B-loads (16B each) per thread per K-tile.
  size_t a_off[2], b_off[2];
#pragma unroll
  for (int j = 0; j < 2; j++) {
    int arow = wid * 32 + j * 16 + (lane >> 2);
    int agr = m0 + arow;
    int acr = (agr < n_e) ? agr : (n_e - 1);
    int atok = (PHASE == 0) ? tok_list[seg + acr] : (seg + acr);
    int chunk = (lane & 3) ^ ((arow >> 1) & 3);  // inverse swizzle on source
    a_off[j] = (size_t)atok * DMODEL + chunk * 8;
    b_off[j] = ((size_t)e * DMODEL + n0 + arow) * DMODEL + chunk * 8;
  }

  f32x4 acc[8][4];
#pragma unroll
  for (int im = 0; im < 8; im++)
#pragma unroll
    for (int in = 0; in < 4; in++) acc[im][in] = (f32x4){0.f, 0.f, 0.f, 0.f};

#define STAGE(BUF, K0)                                                  \
  {                                                                     \
    gl_lds16(Ain + a_off[0] + (K0), &As[BUF][(wid * 32) * 32]);         \
    gl_lds16(Ain + a_off[1] + (K0), &As[BUF][(wid * 32 + 16) * 32]);    \
    gl_lds16(Wt + b_off[0] + (K0), &Bs[BUF][(wid * 32) * 32]);          \
    gl_lds16(Wt + b_off[1] + (K0), &Bs[BUF][(wid * 32 + 16) * 32]);     \
  }

  STAGE(0, 0)
  STAGE(1, 32)

  for (int kt = 0; kt < 32; kt++) {
    int buf = kt & 1;
    if (kt < 31)
      asm volatile("s_waitcnt vmcnt(4)" ::: "memory");  // this tile landed; next in flight
    else
      asm volatile("s_waitcnt vmcnt(0)" ::: "memory");
    __builtin_amdgcn_s_barrier();

    // ---- phase A: B all n-frags + A m-frags 0..3 ----
    bf16x8 bfr[4], af[4];
#pragma unroll
    for (int in = 0; in < 4; in++) {
      int r = wn + in * 16 + ml;
      bfr[in] = *reinterpret_cast<const bf16x8*>(
          &Bs[buf][r * 32 + ((q ^ ((r >> 1) & 3)) * 8)]);
    }
#pragma unroll
    for (int im = 0; im < 4; im++) {
      int r = wm + im * 16 + ml;
      af[im] = *reinterpret_cast<const bf16x8*>(
          &As[buf][r * 32 + ((q ^ ((r >> 1) & 3)) * 8)]);
    }
    asm volatile("s_waitcnt lgkmcnt(0)" ::: "memory");
    __builtin_amdgcn_sched_barrier(0);
    __builtin_amdgcn_s_setprio(1);
#pragma unroll
    for (int im = 0; im < 4; im++)
#pragma unroll
      for (int in = 0; in < 4; in++)
        acc[im][in] = __builtin_amdgcn_mfma_f32_16x16x32_bf16(
            af[im], bfr[in], acc[im][in], 0, 0, 0);
    __builtin_amdgcn_s_setprio(0);

    // ---- phase B: A m-frags 4..7 ----
    bf16x8 ag[4];
#pragma unroll
    for (int im = 0; im < 4; im++) {
      int r = wm + 64 + im * 16 + ml;
      ag[im] = *reinterpret_cast<const bf16x8*>(
          &As[buf][r * 32 + ((q ^ ((r >> 1) & 3)) * 8)]);
    }
    asm volatile("s_waitcnt lgkmcnt(0)" ::: "memory");
    __builtin_amdgcn_sched_barrier(0);
    __builtin_amdgcn_s_setprio(1);
#pragma unroll
    for (int im = 0; im < 4; im++)
#pragma unroll
      for (int in = 0; in < 4; in++)
        acc[im + 4][in] = __builtin_amdgcn_mfma_f32_16x16x32_bf16(
            ag[im], bfr[in], acc[im + 4][in], 0, 0, 0);
    __builtin_amdgcn_s_setprio(0);

    __builtin_amdgcn_s_barrier();  // all reads of buf done across waves
    if (kt < 30) {
      int k0 = (kt + 2) * 32;
      STAGE(buf, k0)
    }
  }
#undef STAGE

  // epilogue (C/D: col=lane&15 -> n, row=quad*4+reg -> m)
#pragma unroll
  for (int in = 0; in < 4; in++) {
    int n = n0 + wn + in * 16 + ml;
    float bv = bias[e * DMODEL + n];
#pragma unroll
    for (int im = 0; im < 8; im++) {
      int mb = m0 + wm + im * 16 + q * 4;  // multiple of 4
      if (PHASE == 0) {
#pragma unroll
        for (int r = 0; r < 4; r++) {
          int gr = mb + r;
          if (gr < n_e) {
            float v = acc[im][in][r] + bv;
            float g = 0.5f * v * (1.f + erff(v * 0.70710678118654752f));
            Hout[(size_t)(seg + gr) * DMODEL + n] =
                (unsigned short)(__hip_bfloat16_raw(__float2bfloat16(g)).x);
          }
        }
      } else {
        float v[4];
        bool ok[4];
#pragma unroll
        for (int r = 0; r < 4; r++) {
          ok[r] = (mb + r) < n_e;
          v[r] = acc[im][in][r] + bv;
        }
        int dp0 = seg + mb;
        if ((seg & 1) == 0) {
#pragma unroll
          for (int r = 0; r < 4; r += 2) {
            if (ok[r] && ok[r + 1])
              atomicAdd(out + (size_t)((dp0 + r) >> 1) * DMODEL + n,
                        v[r] + v[r + 1]);
            else {
              if (ok[r]) atomicAdd(out + (size_t)((dp0 + r) >> 1) * DMODEL + n, v[r]);
              if (ok[r + 1])
                atomicAdd(out + (size_t)((dp0 + r + 1) >> 1) * DMODEL + n, v[r + 1]);
            }
          }
        } else {
          if (ok[0]) atomicAdd(out + (size_t)(dp0 >> 1) * DMODEL + n, v[0]);
          if (ok[1] && ok[2])
            atomicAdd(out + (size_t)((dp0 + 1) >> 1) * DMODEL + n, v[1] + v[2]);
          else {
            if (ok[1]) atomicAdd(out + (size_t)((dp0 + 1) >> 1) * DMODEL + n, v[1]);
            if (ok[2]) atomicAdd(out + (size_t)((dp0 + 2) >> 1) * DMODEL + n, v[2]);
          }
          if (ok[3]) atomicAdd(out + (size_t)((dp0 + 3) >> 1) * DMODEL + n, v[3]);
        }
      }
    }
  }
}

extern "C" void kernel_launch(void* const* d_in, const int* in_sizes, int n_in,
                              void* d_out, int out_size, void* d_ws,
                              size_t ws_size, hipStream_t stream) {
  const float* x  = (const float*)d_in[0];
  const float* wg = (const float*)d_in[1];
  const float* bg = (const float*)d_in[2];
  const float* w1 = (const float*)d_in[3];
  const float* b1 = (const float*)d_in[4];
  const float* w2 = (const float*)d_in[5];
  const float* b2 = (const float*)d_in[6];
  float* out = (float*)d_out;

  char* w = (char*)d_ws;
  int* counts   = (int*)(w);
  int* offsets  = (int*)(w + 256);
  int* eid      = (int*)(w + 512);
  int* tok_list = (int*)(w + 512 + 65536);
  float* partial = (float*)(w + 131584);
  unsigned short* Hbuf = (unsigned short*)(w + 131584 + 8388608);
  unsigned short* Xb   = (unsigned short*)(w + 131584 + 8388608 + 33554432);
  unsigned short* w1t  = (unsigned short*)(w + 131584 + 8388608 + 33554432 + 16777216);
  unsigned short* w2t  = (unsigned short*)(w + 131584 + 8388608 + 33554432 + 16777216 + 67108864);

  hipMemsetAsync(d_ws, 0, 512, stream);
  hipMemsetAsync(d_out, 0, (size_t)NTOK * DMODEL * sizeof(float), stream);

  convert_x<<<dim3(4096), 256, 0, stream>>>(x, Xb);
  transpose_cvt2<<<dim3(8192), 256, 0, stream>>>(w1, w1t);
  transpose_cvt2<<<dim3(8192), 256, 0, stream>>>(w2, w2t);

  gate_partial<<<dim3(256), 256, 0, stream>>>(x, wg, partial);
  gate_top2<<<dim3(32), 256, 0, stream>>>(partial, bg, out + (size_t)NTOK * DMODEL,
                                          eid, counts);
  scan_k<<<1, 64, 0, stream>>>(counts, offsets);
  build_stable<<<dim3(32), 256, 0, stream>>>(eid, offsets, tok_list);

  moe_gemm3<0><<<dim3(512), 512, 0, stream>>>(w1t, b1, Xb, Hbuf, nullptr,
                                              tok_list, offsets, counts);
  moe_gemm3<1><<<dim3(512), 512, 0, stream>>>(w2t, b2, Hbuf, nullptr, out,
                                              tok_list, offsets, counts);
}

// Round 3
// 697.004 us; speedup vs baseline: 1.8640x; 1.8640x over previous
//
#include <hip/hip_runtime.h>
#include <hip/hip_bf16.h>
#include <math.h>

#define NTOK 8192
#define DMODEL 1024
#define NEXP 32

typedef __attribute__((ext_vector_type(8))) short bf16x8;
typedef __attribute__((ext_vector_type(4))) float f32x4;

__device__ __forceinline__ unsigned int pk_bf16(float a, float b) {
  __hip_bfloat162 h = __float22bfloat162_rn(make_float2(a, b));
  union { __hip_bfloat162 h2; unsigned int u; } cv;
  cv.h2 = h;
  return cv.u;
}

__device__ __forceinline__ void gl_lds16(const unsigned short* g, unsigned short* l) {
  __builtin_amdgcn_global_load_lds(
      (const __attribute__((address_space(1))) unsigned int*)g,
      (__attribute__((address_space(3))) unsigned int*)l, 16, 0, 0);
}

// ---------------- x fp32 -> bf16 ----------------
__global__ __launch_bounds__(256) void convert_x(const float* __restrict__ x,
                                                 unsigned short* __restrict__ xb) {
  size_t i = (size_t)(blockIdx.x * 256 + threadIdx.x) * 8;
  float4 f0 = *reinterpret_cast<const float4*>(x + i);
  float4 f1 = *reinterpret_cast<const float4*>(x + i + 4);
  uint4 d;
  d.x = pk_bf16(f0.x, f0.y);
  d.y = pk_bf16(f0.z, f0.w);
  d.z = pk_bf16(f1.x, f1.y);
  d.w = pk_bf16(f1.z, f1.w);
  *reinterpret_cast<uint4*>(xb + i) = d;
}

// ---------------- W [E][K][N] fp32 -> Wt [E][N][K] bf16 ----------------
__global__ __launch_bounds__(256) void transpose_cvt2(const float* __restrict__ w,
                                                      unsigned short* __restrict__ wt) {
  int bid = blockIdx.x;
  int e = bid >> 8;
  int tk = (bid >> 4) & 15;
  int tn = bid & 15;
  const float* src = w + ((size_t)e << 20) + ((size_t)(tk * 64) << 10) + tn * 64;
  unsigned short* dst = wt + ((size_t)e << 20) + ((size_t)(tn * 64) << 10) + tk * 64;
  __shared__ unsigned int Ts[64 * 32];
  int t = threadIdx.x;
  {
    int kp = t >> 3;  // 0..31 (pair of k rows)
    int c8 = t & 7;   // col group of 8
    const float* s0 = src + (size_t)(2 * kp) * 1024 + c8 * 8;
    float4 a0 = *reinterpret_cast<const float4*>(s0);
    float4 a1 = *reinterpret_cast<const float4*>(s0 + 4);
    float4 b0 = *reinterpret_cast<const float4*>(s0 + 1024);
    float4 b1 = *reinterpret_cast<const float4*>(s0 + 1028);
    float av[8] = {a0.x, a0.y, a0.z, a0.w, a1.x, a1.y, a1.z, a1.w};
    float bv[8] = {b0.x, b0.y, b0.z, b0.w, b1.x, b1.y, b1.z, b1.w};
#pragma unroll
    for (int i = 0; i < 8; i++) {
      int n = c8 * 8 + i;
      Ts[n * 32 + (kp ^ (n & 28))] = pk_bf16(av[i], bv[i]);
    }
  }
  __syncthreads();
  {
    int n = t >> 2;
    int kq = t & 3;
#pragma unroll
    for (int h = 0; h < 2; h++) {
      int k4 = kq + h * 4;
      int phys4 = (4 * k4) ^ (n & 28);
      uint4 d = *reinterpret_cast<const uint4*>(&Ts[n * 32 + phys4]);
      *reinterpret_cast<uint4*>(dst + (size_t)n * 1024 + k4 * 8) = d;
    }
  }
}

// ---------------- gating ----------------
__global__ __launch_bounds__(256) void gate_partial(
    const float* __restrict__ x, const float* __restrict__ wg,
    float* __restrict__ partial) {
  __shared__ float Xs[256 * 20];
  int tid = threadIdx.x;
  int part = blockIdx.x >> 5;
  int tb = blockIdx.x & 31;
  int d0 = part * 128;
  float acc[32];
#pragma unroll
  for (int e = 0; e < 32; e++) acc[e] = 0.f;
  for (int ck = 0; ck < 8; ck++) {
    __syncthreads();
#pragma unroll
    for (int q = 0; q < 4; q++) {
      int li = q * 256 + tid;
      int row = li >> 2, j = li & 3;
      float4 v = *reinterpret_cast<const float4*>(
          x + (size_t)(tb * 256 + row) * DMODEL + d0 + ck * 16 + j * 4);
      *reinterpret_cast<float4*>(&Xs[row * 20 + j * 4]) = v;
    }
    __syncthreads();
#pragma unroll
    for (int d4 = 0; d4 < 4; d4++) {
      float4 xv = *reinterpret_cast<const float4*>(&Xs[tid * 20 + d4 * 4]);
      float xs[4] = {xv.x, xv.y, xv.z, xv.w};
#pragma unroll
      for (int dd = 0; dd < 4; dd++) {
        int d = d0 + ck * 16 + d4 * 4 + dd;
#pragma unroll
        for (int e = 0; e < 32; e++) acc[e] += xs[dd] * wg[d * 32 + e];
      }
    }
  }
  float* dst = partial + ((size_t)part * NTOK + tb * 256 + tid) * 32;
#pragma unroll
  for (int e = 0; e < 32; e += 4)
    *reinterpret_cast<float4*>(dst + e) =
        make_float4(acc[e], acc[e + 1], acc[e + 2], acc[e + 3]);
}

__global__ __launch_bounds__(256) void gate_top2(
    const float* __restrict__ partial, const float* __restrict__ bg,
    float* __restrict__ idx_out, int* __restrict__ eid,
    int* __restrict__ counts) {
  int t = blockIdx.x * 256 + threadIdx.x;
  float l[32];
#pragma unroll
  for (int e = 0; e < 32; e++) l[e] = bg[e];
  for (int p = 0; p < 8; p++) {
    const float* src = partial + ((size_t)p * NTOK + t) * 32;
#pragma unroll
    for (int e = 0; e < 32; e += 4) {
      float4 v = *reinterpret_cast<const float4*>(src + e);
      l[e] += v.x; l[e + 1] += v.y; l[e + 2] += v.z; l[e + 3] += v.w;
    }
  }
  int i0 = 0; float v0 = l[0];
#pragma unroll
  for (int e = 1; e < 32; e++)
    if (l[e] > v0) { v0 = l[e]; i0 = e; }
  int i1 = -1; float v1 = -3.0e38f;
#pragma unroll
  for (int e = 0; e < 32; e++)
    if (e != i0 && l[e] > v1) { v1 = l[e]; i1 = e; }
  *reinterpret_cast<float2*>(idx_out + t * 2) = make_float2((float)i0, (float)i1);
  eid[t * 2] = i0;
  eid[t * 2 + 1] = i1;
  atomicAdd(&counts[i0], 1);
  atomicAdd(&counts[i1], 1);
}

__global__ void scan_k(const int* __restrict__ counts, int* __restrict__ offsets) {
  if (threadIdx.x == 0) {
    int s = 0;
    for (int e = 0; e < 32; e++) { offsets[e] = s; s += counts[e]; }
    offsets[32] = s;
  }
}

__global__ __launch_bounds__(256) void build_stable(
    const int* __restrict__ eid, const int* __restrict__ offsets,
    int* __restrict__ tok_list) {
  int e = blockIdx.x;
  int tid = threadIdx.x;
  int lane = tid & 63, wv = tid >> 6;
  __shared__ int wcnt[4];
  int base = offsets[e];
  for (int c = 0; c < 64; c++) {
    int s = c * 256 + tid;
    bool f = (eid[s] == e);
    unsigned long long m = __ballot(f);
    if (lane == 0) wcnt[wv] = __popcll(m);
    __syncthreads();
    int woff = 0;
#pragma unroll
    for (int i = 0; i < 4; i++) woff += (i < wv) ? wcnt[i] : 0;
    int tot = wcnt[0] + wcnt[1] + wcnt[2] + wcnt[3];
    if (f) {
      int rank = woff + __popcll(m & ((1ull << lane) - 1ull));
      tok_list[base + rank] = s >> 1;
    }
    base += tot;
    __syncthreads();
  }
}

// ---------------- ragged GEMM v2: 256m x 256n tile, BK=32, 512 thr (8 waves
// as 2Mx4N, 128x64 per wave), double-buffered, 64KB LDS.
// __launch_bounds__(512, 2): 2 waves/SIMD -> VGPR cap 256. acc[8][4]=128
// VGPRs + frags/addr ~= 200-220 -> fits. (512,4) capped at 128 and spilled
// the accumulators to scratch: 1.2 GB/dispatch scratch traffic, MfmaUtil 3.8%.
// Per K-tile: 2 phases of {ds_read_b128 x8 -> lgkmcnt(0)+sched_barrier ->
// setprio(1) -> 16 MFMA -> setprio(0)}; counted vmcnt(4) once per K-tile.
// LDS swizzle (r>>1)&3: verified conflict-free (SQ_LDS_BANK_CONFLICT=0).
template <int PHASE>
__global__ __launch_bounds__(512, 2) void moe_gemm3(
    const unsigned short* __restrict__ Wt, const float* __restrict__ bias,
    const unsigned short* __restrict__ Ain, unsigned short* __restrict__ Hout,
    float* __restrict__ out, const int* __restrict__ tok_list,
    const int* __restrict__ offsets, const int* __restrict__ counts) {
  // bx = nt*128 + mt*32 + e  (e in low bits -> experts spread over XCDs;
  // sibling tiles of one expert keep same bx%8 -> same XCD slot)
  int bx = blockIdx.x;
  int e = bx & 31;
  int mt = (bx >> 5) & 3;
  int nt = (bx >> 7) & 3;
  int n_e = counts[e];
  int m0 = mt * 256;
  if (m0 >= n_e) return;
  int n0 = nt * 256;
  int seg = offsets[e];

  __shared__ __align__(16) unsigned short As[2][256 * 32];
  __shared__ __align__(16) unsigned short Bs[2][256 * 32];

  int tid = threadIdx.x, lane = tid & 63, wid = tid >> 6;
  int wm = (wid >> 2) * 128, wn = (wid & 3) * 64;
  int ml = lane & 15, q = lane >> 4;

  // staging: wave wid stages A rows [wid*32, wid*32+32) and B rows same,
  // 2 A-loads + 2 B-loads (16B each) per thread per K-tile.
  size_t a_off[2], b_off[2];
#pragma unroll
  for (int j = 0; j < 2; j++) {
    int arow = wid * 32 + j * 16 + (lane >> 2);
    int agr = m0 + arow;
    int acr = (agr < n_e) ? agr : (n_e - 1);
    int atok = (PHASE == 0) ? tok_list[seg + acr] : (seg + acr);
    int chunk = (lane & 3) ^ ((arow >> 1) & 3);  // inverse swizzle on source
    a_off[j] = (size_t)atok * DMODEL + chunk * 8;
    b_off[j] = ((size_t)e * DMODEL + n0 + arow) * DMODEL + chunk * 8;
  }

  f32x4 acc[8][4];
#pragma unroll
  for (int im = 0; im < 8; im++)
#pragma unroll
    for (int in = 0; in < 4; in++) acc[im][in] = (f32x4){0.f, 0.f, 0.f, 0.f};

#define STAGE(BUF, K0)                                                  \
  {                                                                     \
    gl_lds16(Ain + a_off[0] + (K0), &As[BUF][(wid * 32) * 32]);         \
    gl_lds16(Ain + a_off[1] + (K0), &As[BUF][(wid * 32 + 16) * 32]);    \
    gl_lds16(Wt + b_off[0] + (K0), &Bs[BUF][(wid * 32) * 32]);          \
    gl_lds16(Wt + b_off[1] + (K0), &Bs[BUF][(wid * 32 + 16) * 32]);     \
  }

  STAGE(0, 0)
  STAGE(1, 32)

  for (int kt = 0; kt < 32; kt++) {
    int buf = kt & 1;
    if (kt < 31)
      asm volatile("s_waitcnt vmcnt(4)" ::: "memory");  // this tile landed; next in flight
    else
      asm volatile("s_waitcnt vmcnt(0)" ::: "memory");
    __builtin_amdgcn_s_barrier();

    // ---- phase A: B all n-frags + A m-frags 0..3 ----
    bf16x8 bfr[4], af[4];
#pragma unroll
    for (int in = 0; in < 4; in++) {
      int r = wn + in * 16 + ml;
      bfr[in] = *reinterpret_cast<const bf16x8*>(
          &Bs[buf][r * 32 + ((q ^ ((r >> 1) & 3)) * 8)]);
    }
#pragma unroll
    for (int im = 0; im < 4; im++) {
      int r = wm + im * 16 + ml;
      af[im] = *reinterpret_cast<const bf16x8*>(
          &As[buf][r * 32 + ((q ^ ((r >> 1) & 3)) * 8)]);
    }
    asm volatile("s_waitcnt lgkmcnt(0)" ::: "memory");
    __builtin_amdgcn_sched_barrier(0);
    __builtin_amdgcn_s_setprio(1);
#pragma unroll
    for (int im = 0; im < 4; im++)
#pragma unroll
      for (int in = 0; in < 4; in++)
        acc[im][in] = __builtin_amdgcn_mfma_f32_16x16x32_bf16(
            af[im], bfr[in], acc[im][in], 0, 0, 0);
    __builtin_amdgcn_s_setprio(0);

    // ---- phase B: A m-frags 4..7 ----
    bf16x8 ag[4];
#pragma unroll
    for (int im = 0; im < 4; im++) {
      int r = wm + 64 + im * 16 + ml;
      ag[im] = *reinterpret_cast<const bf16x8*>(
          &As[buf][r * 32 + ((q ^ ((r >> 1) & 3)) * 8)]);
    }
    asm volatile("s_waitcnt lgkmcnt(0)" ::: "memory");
    __builtin_amdgcn_sched_barrier(0);
    __builtin_amdgcn_s_setprio(1);
#pragma unroll
    for (int im = 0; im < 4; im++)
#pragma unroll
      for (int in = 0; in < 4; in++)
        acc[im + 4][in] = __builtin_amdgcn_mfma_f32_16x16x32_bf16(
            ag[im], bfr[in], acc[im + 4][in], 0, 0, 0);
    __builtin_amdgcn_s_setprio(0);

    __builtin_amdgcn_s_barrier();  // all reads of buf done across waves
    if (kt < 30) {
      int k0 = (kt + 2) * 32;
      STAGE(buf, k0)
    }
  }
#undef STAGE

  // epilogue (C/D: col=lane&15 -> n, row=quad*4+reg -> m)
#pragma unroll
  for (int in = 0; in < 4; in++) {
    int n = n0 + wn + in * 16 + ml;
    float bv = bias[e * DMODEL + n];
#pragma unroll
    for (int im = 0; im < 8; im++) {
      int mb = m0 + wm + im * 16 + q * 4;  // multiple of 4
      if (PHASE == 0) {
#pragma unroll
        for (int r = 0; r < 4; r++) {
          int gr = mb + r;
          if (gr < n_e) {
            float v = acc[im][in][r] + bv;
            float g = 0.5f * v * (1.f + erff(v * 0.70710678118654752f));
            Hout[(size_t)(seg + gr) * DMODEL + n] =
                (unsigned short)(__hip_bfloat16_raw(__float2bfloat16(g)).x);
          }
        }
      } else {
        float v[4];
        bool ok[4];
#pragma unroll
        for (int r = 0; r < 4; r++) {
          ok[r] = (mb + r) < n_e;
          v[r] = acc[im][in][r] + bv;
        }
        int dp0 = seg + mb;
        if ((seg & 1) == 0) {
#pragma unroll
          for (int r = 0; r < 4; r += 2) {
            if (ok[r] && ok[r + 1])
              atomicAdd(out + (size_t)((dp0 + r) >> 1) * DMODEL + n,
                        v[r] + v[r + 1]);
            else {
              if (ok[r]) atomicAdd(out + (size_t)((dp0 + r) >> 1) * DMODEL + n, v[r]);
              if (ok[r + 1])
                atomicAdd(out + (size_t)((dp0 + r + 1) >> 1) * DMODEL + n, v[r + 1]);
            }
          }
        } else {
          if (ok[0]) atomicAdd(out + (size_t)(dp0 >> 1) * DMODEL + n, v[0]);
          if (ok[1] && ok[2])
            atomicAdd(out + (size_t)((dp0 + 1) >> 1) * DMODEL + n, v[1] + v[2]);
          else {
            if (ok[1]) atomicAdd(out + (size_t)((dp0 + 1) >> 1) * DMODEL + n, v[1]);
            if (ok[2]) atomicAdd(out + (size_t)((dp0 + 2) >> 1) * DMODEL + n, v[2]);
          }
          if (ok[3]) atomicAdd(out + (size_t)((dp0 + 3) >> 1) * DMODEL + n, v[3]);
        }
      }
    }
  }
}

extern "C" void kernel_launch(void* const* d_in, const int* in_sizes, int n_in,
                              void* d_out, int out_size, void* d_ws,
                              size_t ws_size, hipStream_t stream) {
  const float* x  = (const float*)d_in[0];
  const float* wg = (const float*)d_in[1];
  const float* bg = (const float*)d_in[2];
  const float* w1 = (const float*)d_in[3];
  const float* b1 = (const float*)d_in[4];
  const float* w2 = (const float*)d_in[5];
  const float* b2 = (const float*)d_in[6];
  float* out = (float*)d_out;

  char* w = (char*)d_ws;
  int* counts   = (int*)(w);
  int* offsets  = (int*)(w + 256);
  int* eid      = (int*)(w + 512);
  int* tok_list = (int*)(w + 512 + 65536);
  float* partial = (float*)(w + 131584);
  unsigned short* Hbuf = (unsigned short*)(w + 131584 + 8388608);
  unsigned short* Xb   = (unsigned short*)(w + 131584 + 8388608 + 33554432);
  unsigned short* w1t  = (unsigned short*)(w + 131584 + 8388608 + 33554432 + 16777216);
  unsigned short* w2t  = (unsigned short*)(w + 131584 + 8388608 + 33554432 + 16777216 + 67108864);

  hipMemsetAsync(d_ws, 0, 512, stream);
  hipMemsetAsync(d_out, 0, (size_t)NTOK * DMODEL * sizeof(float), stream);

  convert_x<<<dim3(4096), 256, 0, stream>>>(x, Xb);
  transpose_cvt2<<<dim3(8192), 256, 0, stream>>>(w1, w1t);
  transpose_cvt2<<<dim3(8192), 256, 0, stream>>>(w2, w2t);

  gate_partial<<<dim3(256), 256, 0, stream>>>(x, wg, partial);
  gate_top2<<<dim3(32), 256, 0, stream>>>(partial, bg, out + (size_t)NTOK * DMODEL,
                                          eid, counts);
  scan_k<<<1, 64, 0, stream>>>(counts, offsets);
  build_stable<<<dim3(32), 256, 0, stream>>>(eid, offsets, tok_list);

  moe_gemm3<0><<<dim3(512), 512, 0, stream>>>(w1t, b1, Xb, Hbuf, nullptr,
                                              tok_list, offsets, counts);
  moe_gemm3<1><<<dim3(512), 512, 0, stream>>>(w2t, b2, Hbuf, nullptr, out,
                                              tok_list, offsets, counts);
}

// Round 4
// 666.506 us; speedup vs baseline: 1.9493x; 1.0458x over previous
//
#include <hip/hip_runtime.h>
#include <hip/hip_bf16.h>
#include <math.h>

#define NTOK 8192
#define DMODEL 1024
#define NEXP 32

typedef __attribute__((ext_vector_type(8))) short bf16x8;
typedef __attribute__((ext_vector_type(4))) float f32x4;

__device__ __forceinline__ unsigned int pk_bf16(float a, float b) {
  __hip_bfloat162 h = __float22bfloat162_rn(make_float2(a, b));
  union { __hip_bfloat162 h2; unsigned int u; } cv;
  cv.h2 = h;
  return cv.u;
}

__device__ __forceinline__ void gl_lds16(const unsigned short* g, unsigned short* l) {
  __builtin_amdgcn_global_load_lds(
      (const __attribute__((address_space(1))) unsigned int*)g,
      (__attribute__((address_space(3))) unsigned int*)l, 16, 0, 0);
}

// ---------------- x fp32 -> bf16 ----------------
__global__ __launch_bounds__(256) void convert_x(const float* __restrict__ x,
                                                 unsigned short* __restrict__ xb) {
  size_t i = (size_t)(blockIdx.x * 256 + threadIdx.x) * 8;
  float4 f0 = *reinterpret_cast<const float4*>(x + i);
  float4 f1 = *reinterpret_cast<const float4*>(x + i + 4);
  uint4 d;
  d.x = pk_bf16(f0.x, f0.y);
  d.y = pk_bf16(f0.z, f0.w);
  d.z = pk_bf16(f1.x, f1.y);
  d.w = pk_bf16(f1.z, f1.w);
  *reinterpret_cast<uint4*>(xb + i) = d;
}

// ---------------- W [E][K][N] fp32 -> Wt [E][N][K] bf16 ----------------
__global__ __launch_bounds__(256) void transpose_cvt2(const float* __restrict__ w,
                                                      unsigned short* __restrict__ wt) {
  int bid = blockIdx.x;
  int e = bid >> 8;
  int tk = (bid >> 4) & 15;
  int tn = bid & 15;
  const float* src = w + ((size_t)e << 20) + ((size_t)(tk * 64) << 10) + tn * 64;
  unsigned short* dst = wt + ((size_t)e << 20) + ((size_t)(tn * 64) << 10) + tk * 64;
  __shared__ unsigned int Ts[64 * 32];
  int t = threadIdx.x;
  {
    int kp = t >> 3;  // 0..31 (pair of k rows)
    int c8 = t & 7;   // col group of 8
    const float* s0 = src + (size_t)(2 * kp) * 1024 + c8 * 8;
    float4 a0 = *reinterpret_cast<const float4*>(s0);
    float4 a1 = *reinterpret_cast<const float4*>(s0 + 4);
    float4 b0 = *reinterpret_cast<const float4*>(s0 + 1024);
    float4 b1 = *reinterpret_cast<const float4*>(s0 + 1028);
    float av[8] = {a0.x, a0.y, a0.z, a0.w, a1.x, a1.y, a1.z, a1.w};
    float bv[8] = {b0.x, b0.y, b0.z, b0.w, b1.x, b1.y, b1.z, b1.w};
#pragma unroll
    for (int i = 0; i < 8; i++) {
      int n = c8 * 8 + i;
      Ts[n * 32 + (kp ^ (n & 28))] = pk_bf16(av[i], bv[i]);
    }
  }
  __syncthreads();
  {
    int n = t >> 2;
    int kq = t & 3;
#pragma unroll
    for (int h = 0; h < 2; h++) {
      int k4 = kq + h * 4;
      int phys4 = (4 * k4) ^ (n & 28);
      uint4 d = *reinterpret_cast<const uint4*>(&Ts[n * 32 + phys4]);
      *reinterpret_cast<uint4*>(dst + (size_t)n * 1024 + k4 * 8) = d;
    }
  }
}

// ---------------- gating ----------------
__global__ __launch_bounds__(256) void gate_partial(
    const float* __restrict__ x, const float* __restrict__ wg,
    float* __restrict__ partial) {
  __shared__ float Xs[256 * 20];
  int tid = threadIdx.x;
  int part = blockIdx.x >> 5;
  int tb = blockIdx.x & 31;
  int d0 = part * 128;
  float acc[32];
#pragma unroll
  for (int e = 0; e < 32; e++) acc[e] = 0.f;
  for (int ck = 0; ck < 8; ck++) {
    __syncthreads();
#pragma unroll
    for (int q = 0; q < 4; q++) {
      int li = q * 256 + tid;
      int row = li >> 2, j = li & 3;
      float4 v = *reinterpret_cast<const float4*>(
          x + (size_t)(tb * 256 + row) * DMODEL + d0 + ck * 16 + j * 4);
      *reinterpret_cast<float4*>(&Xs[row * 20 + j * 4]) = v;
    }
    __syncthreads();
#pragma unroll
    for (int d4 = 0; d4 < 4; d4++) {
      float4 xv = *reinterpret_cast<const float4*>(&Xs[tid * 20 + d4 * 4]);
      float xs[4] = {xv.x, xv.y, xv.z, xv.w};
#pragma unroll
      for (int dd = 0; dd < 4; dd++) {
        int d = d0 + ck * 16 + d4 * 4 + dd;
#pragma unroll
        for (int e = 0; e < 32; e++) acc[e] += xs[dd] * wg[d * 32 + e];
      }
    }
  }
  float* dst = partial + ((size_t)part * NTOK + tb * 256 + tid) * 32;
#pragma unroll
  for (int e = 0; e < 32; e += 4)
    *reinterpret_cast<float4*>(dst + e) =
        make_float4(acc[e], acc[e + 1], acc[e + 2], acc[e + 3]);
}

__global__ __launch_bounds__(256) void gate_top2(
    const float* __restrict__ partial, const float* __restrict__ bg,
    float* __restrict__ idx_out, int* __restrict__ eid,
    int* __restrict__ counts) {
  int t = blockIdx.x * 256 + threadIdx.x;
  float l[32];
#pragma unroll
  for (int e = 0; e < 32; e++) l[e] = bg[e];
  for (int p = 0; p < 8; p++) {
    const float* src = partial + ((size_t)p * NTOK + t) * 32;
#pragma unroll
    for (int e = 0; e < 32; e += 4) {
      float4 v = *reinterpret_cast<const float4*>(src + e);
      l[e] += v.x; l[e + 1] += v.y; l[e + 2] += v.z; l[e + 3] += v.w;
    }
  }
  int i0 = 0; float v0 = l[0];
#pragma unroll
  for (int e = 1; e < 32; e++)
    if (l[e] > v0) { v0 = l[e]; i0 = e; }
  int i1 = -1; float v1 = -3.0e38f;
#pragma unroll
  for (int e = 0; e < 32; e++)
    if (e != i0 && l[e] > v1) { v1 = l[e]; i1 = e; }
  *reinterpret_cast<float2*>(idx_out + t * 2) = make_float2((float)i0, (float)i1);
  eid[t * 2] = i0;
  eid[t * 2 + 1] = i1;
  atomicAdd(&counts[i0], 1);
  atomicAdd(&counts[i1], 1);
}

__global__ void scan_k(const int* __restrict__ counts, int* __restrict__ offsets) {
  if (threadIdx.x == 0) {
    int s = 0;
    for (int e = 0; e < 32; e++) { offsets[e] = s; s += counts[e]; }
    offsets[32] = s;
  }
}

__global__ __launch_bounds__(256) void build_stable(
    const int* __restrict__ eid, const int* __restrict__ offsets,
    int* __restrict__ tok_list) {
  int e = blockIdx.x;
  int tid = threadIdx.x;
  int lane = tid & 63, wv = tid >> 6;
  __shared__ int wcnt[4];
  int base = offsets[e];
  for (int c = 0; c < 64; c++) {
    int s = c * 256 + tid;
    bool f = (eid[s] == e);
    unsigned long long m = __ballot(f);
    if (lane == 0) wcnt[wv] = __popcll(m);
    __syncthreads();
    int woff = 0;
#pragma unroll
    for (int i = 0; i < 4; i++) woff += (i < wv) ? wcnt[i] : 0;
    int tot = wcnt[0] + wcnt[1] + wcnt[2] + wcnt[3];
    if (f) {
      int rank = woff + __popcll(m & ((1ull << lane) - 1ull));
      tok_list[base + rank] = s >> 1;
    }
    base += tot;
    __syncthreads();
  }
}

// ---------------- ragged GEMM v3: 128m x 256n tile, BK=32, 256 thr (4 waves,
// each 128x64 output, acc[8][4] in AGPR). Triple-buffered LDS (72 KB) with
// depth-2 prefetch and ONE barrier per K-step:
//   { vmcnt(6) ; s_barrier ; STAGE(t+2) ; ds_read ; lgkmcnt(0)+sched_barrier ;
//     setprio(1) 32xMFMA setprio(0) }
// Residency: ~244 unified regs/wave -> 2 waves/SIMD; 4-wave blocks ->
// 2 blocks/CU (LDS 144<=160 KB), ~512 active blocks = 2/CU: co-resident
// blocks hide each other's vmcnt/barrier stalls (round-0's advantage), while
// 128x64/wave halves LDS read bytes/FLOP vs 64x64 (round-0's weakness).
// Race audit: vmcnt(6) BEFORE barrier => all waves' tile-t loads landed before
// any wave reads; barrier separates last read of buf (t-1)%3 from its
// overwrite at t+1; lgkmcnt(0) before MFMA => reads done before overwrite.
// LDS swizzle (r>>1)&3 verified conflict-free (round-3: SQ_LDS_BANK_CONFLICT=0).
template <int PHASE>
__global__ __launch_bounds__(256, 2) void moe_gemm3(
    const unsigned short* __restrict__ Wt, const float* __restrict__ bias,
    const unsigned short* __restrict__ Ain, unsigned short* __restrict__ Hout,
    float* __restrict__ out, const int* __restrict__ tok_list,
    const int* __restrict__ offsets, const int* __restrict__ counts) {
  // bx = nt*256 + mt*32 + e (e in low bits -> experts spread over XCDs)
  int bx = blockIdx.x;
  int e = bx & 31;
  int mt = (bx >> 5) & 7;
  int nt = bx >> 8;
  int n_e = counts[e];
  int m0 = mt * 128;
  if (m0 >= n_e) return;
  int n0 = nt * 256;
  int seg = offsets[e];

  __shared__ __align__(16) unsigned short As[3][128 * 32];
  __shared__ __align__(16) unsigned short Bs[3][256 * 32];

  int tid = threadIdx.x, lane = tid & 63, wid = tid >> 6;
  int wn = wid * 64;
  int ml = lane & 15, q = lane >> 4;

  // staging: wave wid stages A rows [wid*32, wid*32+32) (2 loads) and
  // B rows [wid*64, wid*64+64) (4 loads); 6 x 16B per thread per K-tile.
  size_t a_off[2], b_off[4];
#pragma unroll
  for (int j = 0; j < 2; j++) {
    int arow = wid * 32 + j * 16 + (lane >> 2);
    int agr = m0 + arow;
    int acr = (agr < n_e) ? agr : (n_e - 1);
    int atok = (PHASE == 0) ? tok_list[seg + acr] : (seg + acr);
    int chunk = (lane & 3) ^ ((arow >> 1) & 3);  // inverse swizzle on source
    a_off[j] = (size_t)atok * DMODEL + chunk * 8;
  }
#pragma unroll
  for (int p = 0; p < 4; p++) {
    int brow = wid * 64 + p * 16 + (lane >> 2);
    int chunk = (lane & 3) ^ ((brow >> 1) & 3);
    b_off[p] = ((size_t)e * DMODEL + n0 + brow) * DMODEL + chunk * 8;
  }

  f32x4 acc[8][4];
#pragma unroll
  for (int im = 0; im < 8; im++)
#pragma unroll
    for (int in = 0; in < 4; in++) acc[im][in] = (f32x4){0.f, 0.f, 0.f, 0.f};

#define STAGE(BUF, K0)                                                  \
  {                                                                     \
    gl_lds16(Ain + a_off[0] + (K0), &As[BUF][(wid * 32) * 32]);         \
    gl_lds16(Ain + a_off[1] + (K0), &As[BUF][(wid * 32 + 16) * 32]);    \
    gl_lds16(Wt + b_off[0] + (K0), &Bs[BUF][(wid * 64) * 32]);          \
    gl_lds16(Wt + b_off[1] + (K0), &Bs[BUF][(wid * 64 + 16) * 32]);     \
    gl_lds16(Wt + b_off[2] + (K0), &Bs[BUF][(wid * 64 + 32) * 32]);     \
    gl_lds16(Wt + b_off[3] + (K0), &Bs[BUF][(wid * 64 + 48) * 32]);     \
  }

  STAGE(0, 0)
  STAGE(1, 32)

  for (int kt = 0; kt < 32; kt++) {
    int buf = kt - (kt / 3) * 3;  // kt % 3
    if (kt < 31)
      asm volatile("s_waitcnt vmcnt(6)" ::: "memory");  // tile kt landed; kt+1 in flight
    else
      asm volatile("s_waitcnt vmcnt(0)" ::: "memory");
    __builtin_amdgcn_s_barrier();
    if (kt < 30) {
      int nb = kt + 2;
      int buf2 = nb - (nb / 3) * 3;
      int k0 = nb * 32;
      STAGE(buf2, k0)
    }

    bf16x8 bfr[4], af[8];
#pragma unroll
    for (int in = 0; in < 4; in++) {
      int r = wn + in * 16 + ml;
      bfr[in] = *reinterpret_cast<const bf16x8*>(
          &Bs[buf][r * 32 + ((q ^ ((r >> 1) & 3)) * 8)]);
    }
#pragma unroll
    for (int im = 0; im < 8; im++) {
      int r = im * 16 + ml;
      af[im] = *reinterpret_cast<const bf16x8*>(
          &As[buf][r * 32 + ((q ^ ((r >> 1) & 3)) * 8)]);
    }
    asm volatile("s_waitcnt lgkmcnt(0)" ::: "memory");
    __builtin_amdgcn_sched_barrier(0);
    __builtin_amdgcn_s_setprio(1);
#pragma unroll
    for (int im = 0; im < 8; im++)
#pragma unroll
      for (int in = 0; in < 4; in++)
        acc[im][in] = __builtin_amdgcn_mfma_f32_16x16x32_bf16(
            af[im], bfr[in], acc[im][in], 0, 0, 0);
    __builtin_amdgcn_s_setprio(0);
  }
#undef STAGE

  // epilogue (C/D: col=lane&15 -> n, row=quad*4+reg -> m)
#pragma unroll
  for (int in = 0; in < 4; in++) {
    int n = n0 + wn + in * 16 + ml;
    float bv = bias[e * DMODEL + n];
#pragma unroll
    for (int im = 0; im < 8; im++) {
      int mb = m0 + im * 16 + q * 4;  // multiple of 4
      if (PHASE == 0) {
#pragma unroll
        for (int r = 0; r < 4; r++) {
          int gr = mb + r;
          if (gr < n_e) {
            float v = acc[im][in][r] + bv;
            float g = 0.5f * v * (1.f + erff(v * 0.70710678118654752f));
            Hout[(size_t)(seg + gr) * DMODEL + n] =
                (unsigned short)(__hip_bfloat16_raw(__float2bfloat16(g)).x);
          }
        }
      } else {
        float v[4];
        bool ok[4];
#pragma unroll
        for (int r = 0; r < 4; r++) {
          ok[r] = (mb + r) < n_e;
          v[r] = acc[im][in][r] + bv;
        }
        int dp0 = seg + mb;
        if ((seg & 1) == 0) {
          // pairs (r0,r1),(r2,r3) share out row
#pragma unroll
          for (int r = 0; r < 4; r += 2) {
            if (ok[r] && ok[r + 1])
              atomicAdd(out + (size_t)((dp0 + r) >> 1) * DMODEL + n,
                        v[r] + v[r + 1]);
            else {
              if (ok[r]) atomicAdd(out + (size_t)((dp0 + r) >> 1) * DMODEL + n, v[r]);
              if (ok[r + 1])
                atomicAdd(out + (size_t)((dp0 + r + 1) >> 1) * DMODEL + n, v[r + 1]);
            }
          }
        } else {
          if (ok[0]) atomicAdd(out + (size_t)(dp0 >> 1) * DMODEL + n, v[0]);
          if (ok[1] && ok[2])
            atomicAdd(out + (size_t)((dp0 + 1) >> 1) * DMODEL + n, v[1] + v[2]);
          else {
            if (ok[1]) atomicAdd(out + (size_t)((dp0 + 1) >> 1) * DMODEL + n, v[1]);
            if (ok[2]) atomicAdd(out + (size_t)((dp0 + 2) >> 1) * DMODEL + n, v[2]);
          }
          if (ok[3]) atomicAdd(out + (size_t)((dp0 + 3) >> 1) * DMODEL + n, v[3]);
        }
      }
    }
  }
}

extern "C" void kernel_launch(void* const* d_in, const int* in_sizes, int n_in,
                              void* d_out, int out_size, void* d_ws,
                              size_t ws_size, hipStream_t stream) {
  const float* x  = (const float*)d_in[0];
  const float* wg = (const float*)d_in[1];
  const float* bg = (const float*)d_in[2];
  const float* w1 = (const float*)d_in[3];
  const float* b1 = (const float*)d_in[4];
  const float* w2 = (const float*)d_in[5];
  const float* b2 = (const float*)d_in[6];
  float* out = (float*)d_out;

  char* w = (char*)d_ws;
  int* counts   = (int*)(w);
  int* offsets  = (int*)(w + 256);
  int* eid      = (int*)(w + 512);
  int* tok_list = (int*)(w + 512 + 65536);
  float* partial = (float*)(w + 131584);
  unsigned short* Hbuf = (unsigned short*)(w + 131584 + 8388608);
  unsigned short* Xb   = (unsigned short*)(w + 131584 + 8388608 + 33554432);
  unsigned short* w1t  = (unsigned short*)(w + 131584 + 8388608 + 33554432 + 16777216);
  unsigned short* w2t  = (unsigned short*)(w + 131584 + 8388608 + 33554432 + 16777216 + 67108864);

  hipMemsetAsync(d_ws, 0, 512, stream);
  hipMemsetAsync(d_out, 0, (size_t)NTOK * DMODEL * sizeof(float), stream);

  convert_x<<<dim3(4096), 256, 0, stream>>>(x, Xb);
  transpose_cvt2<<<dim3(8192), 256, 0, stream>>>(w1, w1t);
  transpose_cvt2<<<dim3(8192), 256, 0, stream>>>(w2, w2t);

  gate_partial<<<dim3(256), 256, 0, stream>>>(x, wg, partial);
  gate_top2<<<dim3(32), 256, 0, stream>>>(partial, bg, out + (size_t)NTOK * DMODEL,
                                          eid, counts);
  scan_k<<<1, 64, 0, stream>>>(counts, offsets);
  build_stable<<<dim3(32), 256, 0, stream>>>(eid, offsets, tok_list);

  moe_gemm3<0><<<dim3(1024), 256, 0, stream>>>(w1t, b1, Xb, Hbuf, nullptr,
                                               tok_list, offsets, counts);
  moe_gemm3<1><<<dim3(1024), 256, 0, stream>>>(w2t, b2, Hbuf, nullptr, out,
                                               tok_list, offsets, counts);
}

// Round 5
// 609.555 us; speedup vs baseline: 2.1314x; 1.0934x over previous
//
#include <hip/hip_runtime.h>
#include <hip/hip_bf16.h>
#include <math.h>

#define NTOK 8192
#define DMODEL 1024
#define NEXP 32

typedef __attribute__((ext_vector_type(8))) short bf16x8;
typedef __attribute__((ext_vector_type(4))) float f32x4;

__device__ __forceinline__ unsigned int pk_bf16(float a, float b) {
  __hip_bfloat162 h = __float22bfloat162_rn(make_float2(a, b));
  union { __hip_bfloat162 h2; unsigned int u; } cv;
  cv.h2 = h;
  return cv.u;
}

__device__ __forceinline__ void gl_lds16(const unsigned short* g, unsigned short* l) {
  __builtin_amdgcn_global_load_lds(
      (const __attribute__((address_space(1))) unsigned int*)g,
      (__attribute__((address_space(3))) unsigned int*)l, 16, 0, 0);
}

// ---------------- W [E][K][N] fp32 -> Wt [E][N][K] bf16 ----------------
__global__ __launch_bounds__(256) void transpose_cvt2(const float* __restrict__ w,
                                                      unsigned short* __restrict__ wt) {
  int bid = blockIdx.x;
  int e = bid >> 8;
  int tk = (bid >> 4) & 15;
  int tn = bid & 15;
  const float* src = w + ((size_t)e << 20) + ((size_t)(tk * 64) << 10) + tn * 64;
  unsigned short* dst = wt + ((size_t)e << 20) + ((size_t)(tn * 64) << 10) + tk * 64;
  __shared__ unsigned int Ts[64 * 32];
  int t = threadIdx.x;
  {
    int kp = t >> 3;  // 0..31 (pair of k rows)
    int c8 = t & 7;   // col group of 8
    const float* s0 = src + (size_t)(2 * kp) * 1024 + c8 * 8;
    float4 a0 = *reinterpret_cast<const float4*>(s0);
    float4 a1 = *reinterpret_cast<const float4*>(s0 + 4);
    float4 b0 = *reinterpret_cast<const float4*>(s0 + 1024);
    float4 b1 = *reinterpret_cast<const float4*>(s0 + 1028);
    float av[8] = {a0.x, a0.y, a0.z, a0.w, a1.x, a1.y, a1.z, a1.w};
    float bv[8] = {b0.x, b0.y, b0.z, b0.w, b1.x, b1.y, b1.z, b1.w};
#pragma unroll
    for (int i = 0; i < 8; i++) {
      int n = c8 * 8 + i;
      Ts[n * 32 + (kp ^ (n & 28))] = pk_bf16(av[i], bv[i]);
    }
  }
  __syncthreads();
  {
    int n = t >> 2;
    int kq = t & 3;
#pragma unroll
    for (int h = 0; h < 2; h++) {
      int k4 = kq + h * 4;
      int phys4 = (4 * k4) ^ (n & 28);
      uint4 d = *reinterpret_cast<const uint4*>(&Ts[n * 32 + phys4]);
      *reinterpret_cast<uint4*>(dst + (size_t)n * 1024 + k4 * 8) = d;
    }
  }
}

// ---------------- gating (fused x fp32 -> bf16 conversion) ----------------
// Each (part, tb) block streams x tokens [tb*256,+256) over d-slice
// [part*128,+128) exactly once -> also emits the bf16 copy of that slice,
// eliminating the separate convert_x pass (50 MB + one dispatch).
__global__ __launch_bounds__(256) void gate_partial(
    const float* __restrict__ x, const float* __restrict__ wg,
    float* __restrict__ partial, unsigned short* __restrict__ xb) {
  __shared__ float Xs[256 * 20];
  int tid = threadIdx.x;
  int part = blockIdx.x >> 5;
  int tb = blockIdx.x & 31;
  int d0 = part * 128;
  float acc[32];
#pragma unroll
  for (int e = 0; e < 32; e++) acc[e] = 0.f;
  for (int ck = 0; ck < 8; ck++) {
    __syncthreads();
#pragma unroll
    for (int q = 0; q < 4; q++) {
      int li = q * 256 + tid;
      int row = li >> 2, j = li & 3;
      int col = d0 + ck * 16 + j * 4;
      float4 v = *reinterpret_cast<const float4*>(
          x + (size_t)(tb * 256 + row) * DMODEL + col);
      *reinterpret_cast<float4*>(&Xs[row * 20 + j * 4]) = v;
      uint2 d2 = make_uint2(pk_bf16(v.x, v.y), pk_bf16(v.z, v.w));
      *reinterpret_cast<uint2*>(xb + (size_t)(tb * 256 + row) * DMODEL + col) = d2;
    }
    __syncthreads();
#pragma unroll
    for (int d4 = 0; d4 < 4; d4++) {
      float4 xv = *reinterpret_cast<const float4*>(&Xs[tid * 20 + d4 * 4]);
      float xs[4] = {xv.x, xv.y, xv.z, xv.w};
#pragma unroll
      for (int dd = 0; dd < 4; dd++) {
        int d = d0 + ck * 16 + d4 * 4 + dd;
#pragma unroll
        for (int e = 0; e < 32; e++) acc[e] += xs[dd] * wg[d * 32 + e];
      }
    }
  }
  float* dst = partial + ((size_t)part * NTOK + tb * 256 + tid) * 32;
#pragma unroll
  for (int e = 0; e < 32; e += 4)
    *reinterpret_cast<float4*>(dst + e) =
        make_float4(acc[e], acc[e + 1], acc[e + 2], acc[e + 3]);
}

__global__ __launch_bounds__(256) void gate_top2(
    const float* __restrict__ partial, const float* __restrict__ bg,
    float* __restrict__ idx_out, int* __restrict__ eid,
    int* __restrict__ counts) {
  int t = blockIdx.x * 256 + threadIdx.x;
  float l[32];
#pragma unroll
  for (int e = 0; e < 32; e++) l[e] = bg[e];
  for (int p = 0; p < 8; p++) {
    const float* src = partial + ((size_t)p * NTOK + t) * 32;
#pragma unroll
    for (int e = 0; e < 32; e += 4) {
      float4 v = *reinterpret_cast<const float4*>(src + e);
      l[e] += v.x; l[e + 1] += v.y; l[e + 2] += v.z; l[e + 3] += v.w;
    }
  }
  int i0 = 0; float v0 = l[0];
#pragma unroll
  for (int e = 1; e < 32; e++)
    if (l[e] > v0) { v0 = l[e]; i0 = e; }
  int i1 = -1; float v1 = -3.0e38f;
#pragma unroll
  for (int e = 0; e < 32; e++)
    if (e != i0 && l[e] > v1) { v1 = l[e]; i1 = e; }
  *reinterpret_cast<float2*>(idx_out + t * 2) = make_float2((float)i0, (float)i1);
  eid[t * 2] = i0;
  eid[t * 2 + 1] = i1;
  atomicAdd(&counts[i0], 1);
  atomicAdd(&counts[i1], 1);
}

__global__ void scan_k(const int* __restrict__ counts, int* __restrict__ offsets) {
  if (threadIdx.x == 0) {
    int s = 0;
    for (int e = 0; e < 32; e++) { offsets[e] = s; s += counts[e]; }
    offsets[32] = s;
  }
}

// 512 threads, 32 iterations (was 256x64): halves the barrier round-trips.
__global__ __launch_bounds__(512) void build_stable(
    const int* __restrict__ eid, const int* __restrict__ offsets,
    int* __restrict__ tok_list) {
  int e = blockIdx.x;
  int tid = threadIdx.x;
  int lane = tid & 63, wv = tid >> 6;
  __shared__ int wcnt[8];
  int base = offsets[e];
  for (int c = 0; c < 32; c++) {
    int s = c * 512 + tid;
    bool f = (eid[s] == e);
    unsigned long long m = __ballot(f);
    if (lane == 0) wcnt[wv] = __popcll(m);
    __syncthreads();
    int woff = 0;
#pragma unroll
    for (int i = 0; i < 8; i++) woff += (i < wv) ? wcnt[i] : 0;
    int tot = 0;
#pragma unroll
    for (int i = 0; i < 8; i++) tot += wcnt[i];
    if (f) {
      int rank = woff + __popcll(m & ((1ull << lane) - 1ull));
      tok_list[base + rank] = s >> 1;
    }
    base += tot;
    __syncthreads();
  }
}

// ---------------- ragged GEMM (round-0 structure, proven 104 us): 128m x
// 256n tile, 512 thr (8 waves of 64x64 -> 2-4 waves/SIMD resident; the
// r3/r4 experiments showed co-resident wave count dominates per-wave tile
// size for this K=1024 latency-bound GEMM), BK=32, explicit double-buffer,
// raw s_barrier + vmcnt(3).
// One change vs round-0: LDS swizzle (r>>1)&3 on BOTH staging-source and
// read side -- r3/r4 measured SQ_LDS_BANK_CONFLICT 4.69M -> 0 with it.
template <int PHASE>
__global__ __launch_bounds__(512, 4) void moe_gemm3(
    const unsigned short* __restrict__ Wt, const float* __restrict__ bias,
    const unsigned short* __restrict__ Ain, unsigned short* __restrict__ Hout,
    float* __restrict__ out, const int* __restrict__ tok_list,
    const int* __restrict__ offsets, const int* __restrict__ counts) {
  // bx = nt*512 + mt*64 + e  (e in low bits -> experts spread over XCDs)
  int bx = blockIdx.x;
  int e = bx & 31;
  int mt = (bx >> 5) & 7;
  int nt = bx >> 8;
  int n_e = counts[e];
  int m0 = mt * 128;
  if (m0 >= n_e) return;
  int n0 = nt * 256;
  int seg = offsets[e];

  __shared__ __align__(16) unsigned short As[2][128 * 32];
  __shared__ __align__(16) unsigned short Bs[2][256 * 32];

  int tid = threadIdx.x, lane = tid & 63, wid = tid >> 6;
  int wm = (wid >> 2) * 64, wn = (wid & 3) * 64;
  int ml = lane & 15, q = lane >> 4;

  // per-thread staging sources (1 A-instr, 2 B-instrs per wave per tile)
  int arow = wid * 16 + (lane >> 2);
  int agr = m0 + arow;
  int acr = (agr < n_e) ? agr : (n_e - 1);
  int atok = (PHASE == 0) ? tok_list[seg + acr] : (seg + acr);
  size_t a_off = (size_t)atok * DMODEL + (((lane & 3) ^ ((arow >> 1) & 3)) * 8);
  size_t b_off[2];
#pragma unroll
  for (int p = 0; p < 2; p++) {
    int brow = wid * 32 + p * 16 + (lane >> 2);
    b_off[p] = ((size_t)e * DMODEL + n0 + brow) * DMODEL +
               (((lane & 3) ^ ((brow >> 1) & 3)) * 8);
  }

  f32x4 acc[4][4];
#pragma unroll
  for (int im = 0; im < 4; im++)
#pragma unroll
    for (int in = 0; in < 4; in++) acc[im][in] = (f32x4){0.f, 0.f, 0.f, 0.f};

#define STAGE(BUF, K0)                                                \
  {                                                                   \
    gl_lds16(Ain + a_off + (K0), &As[BUF][wid * 512]);                \
    gl_lds16(Wt + b_off[0] + (K0), &Bs[BUF][(wid * 2) * 512]);        \
    gl_lds16(Wt + b_off[1] + (K0), &Bs[BUF][(wid * 2 + 1) * 512]);    \
  }

  STAGE(0, 0)
  STAGE(1, 32)

  for (int kt = 0; kt < 32; kt++) {
    int buf = kt & 1;
    if (kt < 31)
      asm volatile("s_waitcnt vmcnt(3)" ::: "memory");
    else
      asm volatile("s_waitcnt vmcnt(0)" ::: "memory");
    __builtin_amdgcn_s_barrier();

    bf16x8 af[4], bfr[4];
#pragma unroll
    for (int im = 0; im < 4; im++) {
      int r = wm + im * 16 + ml;
      af[im] = *reinterpret_cast<const bf16x8*>(
          &As[buf][r * 32 + ((q ^ ((r >> 1) & 3)) * 8)]);
    }
#pragma unroll
    for (int in = 0; in < 4; in++) {
      int r = wn + in * 16 + ml;
      bfr[in] = *reinterpret_cast<const bf16x8*>(
          &Bs[buf][r * 32 + ((q ^ ((r >> 1) & 3)) * 8)]);
    }
#pragma unroll
    for (int im = 0; im < 4; im++)
#pragma unroll
      for (int in = 0; in < 4; in++)
        acc[im][in] = __builtin_amdgcn_mfma_f32_16x16x32_bf16(
            af[im], bfr[in], acc[im][in], 0, 0, 0);

    asm volatile("s_waitcnt lgkmcnt(0)" ::: "memory");
    __builtin_amdgcn_s_barrier();
    if (kt < 30) {
      int k0 = (kt + 2) * 32;
      STAGE(buf, k0)
    }
  }
#undef STAGE

  // epilogue (C/D: col=lane&15, row=quad*4+reg)
#pragma unroll
  for (int in = 0; in < 4; in++) {
    int n = n0 + wn + in * 16 + ml;
    float bv = bias[e * DMODEL + n];
#pragma unroll
    for (int im = 0; im < 4; im++) {
      int mb = m0 + wm + im * 16 + q * 4;  // even
      if (PHASE == 0) {
#pragma unroll
        for (int r = 0; r < 4; r++) {
          int gr = mb + r;
          if (gr < n_e) {
            float v = acc[im][in][r] + bv;
            float g = 0.5f * v * (1.f + erff(v * 0.70710678118654752f));
            Hout[(size_t)(seg + gr) * DMODEL + n] =
                (unsigned short)(__hip_bfloat16_raw(__float2bfloat16(g)).x);
          }
        }
      } else {
        float v[4];
        bool ok[4];
#pragma unroll
        for (int r = 0; r < 4; r++) {
          ok[r] = (mb + r) < n_e;
          v[r] = acc[im][in][r] + bv;
        }
        int dp0 = seg + mb;
        if ((seg & 1) == 0) {
          // pairs (r0,r1),(r2,r3) share out row
#pragma unroll
          for (int r = 0; r < 4; r += 2) {
            if (ok[r] && ok[r + 1])
              atomicAdd(out + (size_t)((dp0 + r) >> 1) * DMODEL + n,
                        v[r] + v[r + 1]);
            else {
              if (ok[r]) atomicAdd(out + (size_t)((dp0 + r) >> 1) * DMODEL + n, v[r]);
              if (ok[r + 1])
                atomicAdd(out + (size_t)((dp0 + r + 1) >> 1) * DMODEL + n, v[r + 1]);
            }
          }
        } else {
          if (ok[0]) atomicAdd(out + (size_t)(dp0 >> 1) * DMODEL + n, v[0]);
          if (ok[1] && ok[2])
            atomicAdd(out + (size_t)((dp0 + 1) >> 1) * DMODEL + n, v[1] + v[2]);
          else {
            if (ok[1]) atomicAdd(out + (size_t)((dp0 + 1) >> 1) * DMODEL + n, v[1]);
            if (ok[2]) atomicAdd(out + (size_t)((dp0 + 2) >> 1) * DMODEL + n, v[2]);
          }
          if (ok[3]) atomicAdd(out + (size_t)((dp0 + 3) >> 1) * DMODEL + n, v[3]);
        }
      }
    }
  }
}

extern "C" void kernel_launch(void* const* d_in, const int* in_sizes, int n_in,
                              void* d_out, int out_size, void* d_ws,
                              size_t ws_size, hipStream_t stream) {
  const float* x  = (const float*)d_in[0];
  const float* wg = (const float*)d_in[1];
  const float* bg = (const float*)d_in[2];
  const float* w1 = (const float*)d_in[3];
  const float* b1 = (const float*)d_in[4];
  const float* w2 = (const float*)d_in[5];
  const float* b2 = (const float*)d_in[6];
  float* out = (float*)d_out;

  char* w = (char*)d_ws;
  int* counts   = (int*)(w);
  int* offsets  = (int*)(w + 256);
  int* eid      = (int*)(w + 512);
  int* tok_list = (int*)(w + 512 + 65536);
  float* partial = (float*)(w + 131584);
  unsigned short* Hbuf = (unsigned short*)(w + 131584 + 8388608);
  unsigned short* Xb   = (unsigned short*)(w + 131584 + 8388608 + 33554432);
  unsigned short* w1t  = (unsigned short*)(w + 131584 + 8388608 + 33554432 + 16777216);
  unsigned short* w2t  = (unsigned short*)(w + 131584 + 8388608 + 33554432 + 16777216 + 67108864);

  hipMemsetAsync(d_ws, 0, 512, stream);
  hipMemsetAsync(d_out, 0, (size_t)NTOK * DMODEL * sizeof(float), stream);

  transpose_cvt2<<<dim3(8192), 256, 0, stream>>>(w1, w1t);
  transpose_cvt2<<<dim3(8192), 256, 0, stream>>>(w2, w2t);

  gate_partial<<<dim3(256), 256, 0, stream>>>(x, wg, partial, Xb);
  gate_top2<<<dim3(32), 256, 0, stream>>>(partial, bg, out + (size_t)NTOK * DMODEL,
                                          eid, counts);
  scan_k<<<1, 64, 0, stream>>>(counts, offsets);
  build_stable<<<dim3(32), 512, 0, stream>>>(eid, offsets, tok_list);

  moe_gemm3<0><<<dim3(1024), 512, 0, stream>>>(w1t, b1, Xb, Hbuf, nullptr,
                                               tok_list, offsets, counts);
  moe_gemm3<1><<<dim3(1024), 512, 0, stream>>>(w2t, b2, Hbuf, nullptr, out,
                                               tok_list, offsets, counts);
}